// Round 1
// baseline (11606.874 us; speedup 1.0000x reference)
//
#include <hip/hip_runtime.h>
#include <math.h>

#define DEPTH 6
#define DIM 1024
#define HEADS 16
#define DH 64
#define INNER 2730
#define INNER2 5460
#define BATCH 2
#define SEQ 1024
#define TOK (BATCH*SEQ)

// ---------------- copy ----------------
__global__ void copy_kernel(float* __restrict__ dst, const float* __restrict__ src, int n) {
  int i = blockIdx.x * blockDim.x + threadIdx.x;
  if (i < n) dst[i] = src[i];
}

// ---------------- rel-pos bias table: bias_t[h][d], d = i-j in [0,1024) ----------------
__global__ void bias_kernel(const float* __restrict__ rel_emb, float* __restrict__ bias_t) {
  int d = blockIdx.x * blockDim.x + threadIdx.x;
  if (d >= SEQ) return;
  int bucket;
  if (d < 16) {
    bucket = d;
  } else {
    float nf = (float)d;
    int vl = 16 + (int)(logf(nf / 16.0f) / 2.0794415416798357f * 16.0f);
    bucket = vl < 31 ? vl : 31;
  }
  for (int h = 0; h < HEADS; h++)
    bias_t[h * SEQ + d] = rel_emb[bucket * HEADS + h];
}

// ---------------- LayerNorm (one block per row) ----------------
__global__ __launch_bounds__(256) void ln_kernel(const float* __restrict__ in,
                                                 const float* __restrict__ g,
                                                 float* __restrict__ out, int cols) {
  int row = blockIdx.x;
  const float* rp = in + (size_t)row * cols;
  float s = 0.f, ss = 0.f;
  for (int c = threadIdx.x; c < cols; c += blockDim.x) {
    float v = rp[c];
    s += v; ss += v * v;
  }
#pragma unroll
  for (int off = 32; off; off >>= 1) {
    s  += __shfl_down(s, off, 64);
    ss += __shfl_down(ss, off, 64);
  }
  __shared__ float l1[8], l2[8];
  int wid = threadIdx.x >> 6, lane = threadIdx.x & 63;
  if (lane == 0) { l1[wid] = s; l2[wid] = ss; }
  __syncthreads();
  if (threadIdx.x == 0) {
    float a = 0.f, b = 0.f;
    int nw = blockDim.x >> 6;
    for (int i = 0; i < nw; i++) { a += l1[i]; b += l2[i]; }
    float m = a / cols;
    float v = b / cols - m * m;
    l1[0] = m;
    l2[0] = rsqrtf(v + 1e-5f);
  }
  __syncthreads();
  float m = l1[0], r = l2[0];
  float* op = out + (size_t)row * cols;
  for (int c = threadIdx.x; c < cols; c += blockDim.x)
    op[c] = (rp[c] - m) * r * g[c];
}

// ---------------- generic fp32 GEMM: C = scale*(A@B) (+ Cin) ----------------
#define BM 64
#define BN 64
#define BK 16

template <bool ADD>
__global__ __launch_bounds__(256) void gemm_kernel(const float* __restrict__ A,
                                                   const float* __restrict__ Bm,
                                                   const float* __restrict__ Cin,
                                                   float* __restrict__ C,
                                                   int M, int N, int K, float scale) {
  __shared__ float As[BK][BM + 4];
  __shared__ float Bs[BK][BN + 4];
  int tid = threadIdx.x;
  int tx = tid & 15, ty = tid >> 4;
  int row0 = blockIdx.y * BM, col0 = blockIdx.x * BN;
  float acc[4][4] = {};
  for (int k0 = 0; k0 < K; k0 += BK) {
    for (int i = tid; i < BM * BK; i += 256) {
      int r = i >> 4, c = i & 15;
      int gr = row0 + r, gc = k0 + c;
      As[c][r] = (gr < M && gc < K) ? A[(size_t)gr * K + gc] : 0.f;
    }
    for (int i = tid; i < BK * BN; i += 256) {
      int r = i >> 6, c = i & 63;
      int gr = k0 + r, gc = col0 + c;
      Bs[r][c] = (gr < K && gc < N) ? Bm[(size_t)gr * N + gc] : 0.f;
    }
    __syncthreads();
#pragma unroll
    for (int k = 0; k < BK; k++) {
      float a[4], b[4];
#pragma unroll
      for (int i = 0; i < 4; i++) a[i] = As[k][ty * 4 + i];
#pragma unroll
      for (int j = 0; j < 4; j++) b[j] = Bs[k][tx * 4 + j];
#pragma unroll
      for (int i = 0; i < 4; i++)
#pragma unroll
        for (int j = 0; j < 4; j++) acc[i][j] += a[i] * b[j];
    }
    __syncthreads();
  }
#pragma unroll
  for (int i = 0; i < 4; i++) {
    int gr = row0 + ty * 4 + i;
    if (gr >= M) continue;
#pragma unroll
    for (int j = 0; j < 4; j++) {
      int gc = col0 + tx * 4 + j;
      if (gc >= N) continue;
      float v = acc[i][j] * scale;
      if (ADD) v += Cin[(size_t)gr * N + gc];
      C[(size_t)gr * N + gc] = v;
    }
  }
}

// ---------------- causal conv(3) + GLU(gelu exact) ----------------
__global__ void convglu_kernel(const float* __restrict__ h1, const float* __restrict__ cw,
                               float* __restrict__ out) {
  int idx = blockIdx.x * blockDim.x + threadIdx.x;
  const int total = TOK * INNER;
  if (idx >= total) return;
  int c = idx % INNER;
  int t = idx / INNER;   // token = b*SEQ + n
  int n = t % SEQ;
  const float* base = h1 + (size_t)t * INNER2;
  float a0 = (n >= 2) ? base[c - 2 * INNER2] : 0.f;
  float a1 = (n >= 1) ? base[c - INNER2] : 0.f;
  float a2 = base[c];
  int cg = c + INNER;
  float g0 = (n >= 2) ? base[cg - 2 * INNER2] : 0.f;
  float g1 = (n >= 1) ? base[cg - INNER2] : 0.f;
  float g2 = base[cg];
  float av = a0 * cw[c * 3] + a1 * cw[c * 3 + 1] + a2 * cw[c * 3 + 2];
  float gv = g0 * cw[cg * 3] + g1 * cw[cg * 3 + 1] + g2 * cw[cg * 3 + 2];
  float gl = 0.5f * gv * (1.0f + erff(gv * 0.70710678118654752f));
  out[idx] = gl * av;
}

// ---------------- flash-style causal attention with rel-pos bias ----------------
// grid: (BATCH*HEADS, SEQ/64); block 256. q: (B,N,H*DH) pre-scaled; kv: (B,N,128).
__global__ __launch_bounds__(256) void attn_kernel(const float* __restrict__ q,
                                                   const float* __restrict__ kv,
                                                   const float* __restrict__ bias_t,
                                                   float* __restrict__ o) {
  __shared__ float Qs[64][68];
  __shared__ float KVs[64][68];
  __shared__ float Ss[64][68];
  __shared__ float mrow[64], lrow[64], arow[64];
  int bh = blockIdx.x;
  int b = bh >> 4, h = bh & 15;
  int qt = blockIdx.y;
  int tid = threadIdx.x;
  int tx = tid & 15, ty = tid >> 4;

  for (int i = tid; i < 64 * 64; i += 256) {
    int r = i >> 6, d = i & 63;
    Qs[r][d] = q[((size_t)(b * SEQ + qt * 64 + r)) * 1024 + h * 64 + d];
  }
  if (tid < 64) { mrow[tid] = -1e30f; lrow[tid] = 0.f; }
  float acc[4][4] = {};
  __syncthreads();

  for (int kc = 0; kc <= qt; kc++) {
    // load K chunk
    for (int i = tid; i < 64 * 64; i += 256) {
      int r = i >> 6, d = i & 63;
      KVs[r][d] = kv[((size_t)(b * SEQ + kc * 64 + r)) * 128 + d];
    }
    __syncthreads();
    // S = Q @ K^T
    float s[4][4] = {};
#pragma unroll 8
    for (int d = 0; d < 64; d++) {
      float a[4], bb[4];
#pragma unroll
      for (int i = 0; i < 4; i++) a[i] = Qs[ty * 4 + i][d];
#pragma unroll
      for (int j = 0; j < 4; j++) bb[j] = KVs[tx * 4 + j][d];
#pragma unroll
      for (int i = 0; i < 4; i++)
#pragma unroll
        for (int j = 0; j < 4; j++) s[i][j] += a[i] * bb[j];
    }
#pragma unroll
    for (int i = 0; i < 4; i++) {
      int qi = qt * 64 + ty * 4 + i;
#pragma unroll
      for (int j = 0; j < 4; j++) {
        int kj = kc * 64 + tx * 4 + j;
        Ss[ty * 4 + i][tx * 4 + j] =
            (kj > qi) ? -1e30f : s[i][j] + bias_t[h * SEQ + (qi - kj)];
      }
    }
    __syncthreads();
    // overlap: load V chunk into KVs (K no longer needed) + per-row softmax update
    for (int i = tid; i < 64 * 64; i += 256) {
      int r = i >> 6, d = i & 63;
      KVs[r][d] = kv[((size_t)(b * SEQ + kc * 64 + r)) * 128 + 64 + d];
    }
    if (tid < 64) {
      float m = mrow[tid], l = lrow[tid];
      float cm = m;
      for (int c = 0; c < 64; c++) cm = fmaxf(cm, Ss[tid][c]);
      float alpha = expf(m - cm);
      float sum = 0.f;
      for (int c = 0; c < 64; c++) {
        float p = expf(Ss[tid][c] - cm);
        Ss[tid][c] = p;
        sum += p;
      }
      mrow[tid] = cm;
      lrow[tid] = l * alpha + sum;
      arow[tid] = alpha;
    }
    __syncthreads();
    // O = O*alpha + P @ V
#pragma unroll
    for (int i = 0; i < 4; i++) {
      float al = arow[ty * 4 + i];
#pragma unroll
      for (int j = 0; j < 4; j++) acc[i][j] *= al;
    }
#pragma unroll 8
    for (int c = 0; c < 64; c++) {
      float p[4], vv[4];
#pragma unroll
      for (int i = 0; i < 4; i++) p[i] = Ss[ty * 4 + i][c];
#pragma unroll
      for (int j = 0; j < 4; j++) vv[j] = KVs[c][tx * 4 + j];
#pragma unroll
      for (int i = 0; i < 4; i++)
#pragma unroll
        for (int j = 0; j < 4; j++) acc[i][j] += p[i] * vv[j];
    }
    __syncthreads();
  }

#pragma unroll
  for (int i = 0; i < 4; i++) {
    int r = ty * 4 + i;
    float inv = 1.0f / lrow[r];
#pragma unroll
    for (int j = 0; j < 4; j++)
      o[((size_t)(b * SEQ + qt * 64 + r)) * 1024 + h * 64 + tx * 4 + j] = acc[i][j] * inv;
  }
}

// ---------------- launch ----------------
extern "C" void kernel_launch(void* const* d_in, const int* in_sizes, int n_in,
                              void* d_out, int out_size, void* d_ws, size_t ws_size,
                              hipStream_t stream) {
  const float* x_in    = (const float*)d_in[0];
  const float* rel_emb = (const float*)d_in[1];
  const float* qn_g    = (const float*)d_in[2];
  const float* wq      = (const float*)d_in[3];
  const float* wkv     = (const float*)d_in[4];
  const float* wo      = (const float*)d_in[5];
  const float* ln1_g   = (const float*)d_in[6];
  const float* w1      = (const float*)d_in[7];
  const float* convw   = (const float*)d_in[8];
  const float* ln2_g   = (const float*)d_in[9];
  const float* w2      = (const float*)d_in[10];
  const float* final_g = (const float*)d_in[11];
  float* out = (float*)d_out;

  float* ws = (float*)d_ws;
  float* xbuf   = ws; ws += (size_t)TOK * DIM;
  float* hbuf   = ws; ws += (size_t)TOK * DIM;
  float* qbuf   = ws; ws += (size_t)TOK * DIM;
  float* kvbuf  = ws; ws += (size_t)TOK * 128;
  float* obuf   = ws; ws += (size_t)TOK * DIM;
  float* h1buf  = ws; ws += (size_t)TOK * INNER2;
  float* gbuf   = ws; ws += (size_t)TOK * INNER;
  float* bias_t = ws; ws += (size_t)HEADS * SEQ;

  copy_kernel<<<(TOK * DIM + 255) / 256, 256, 0, stream>>>(xbuf, x_in, TOK * DIM);
  bias_kernel<<<4, 256, 0, stream>>>(rel_emb, bias_t);

  for (int l = 0; l < DEPTH; l++) {
    // h = LN(x, qn_g)
    ln_kernel<<<TOK, 256, 0, stream>>>(xbuf, qn_g + l * DIM, hbuf, DIM);
    // q = h@wq * scale
    gemm_kernel<false><<<dim3(DIM / 64, TOK / 64), 256, 0, stream>>>(
        hbuf, wq + (size_t)l * DIM * DIM, nullptr, qbuf, TOK, DIM, DIM, 0.125f);
    // kv = h@wkv
    gemm_kernel<false><<<dim3(2, TOK / 64), 256, 0, stream>>>(
        hbuf, wkv + (size_t)l * DIM * 128, nullptr, kvbuf, TOK, 128, DIM, 1.0f);
    // attention
    attn_kernel<<<dim3(BATCH * HEADS, SEQ / 64), 256, 0, stream>>>(qbuf, kvbuf, bias_t, obuf);
    // x = o@wo + x
    gemm_kernel<true><<<dim3(DIM / 64, TOK / 64), 256, 0, stream>>>(
        obuf, wo + (size_t)l * DIM * DIM, xbuf, xbuf, TOK, DIM, DIM, 1.0f);
    // h = LN(x, ln1_g)
    ln_kernel<<<TOK, 256, 0, stream>>>(xbuf, ln1_g + l * DIM, hbuf, DIM);
    // h1 = h@w1
    gemm_kernel<false><<<dim3((INNER2 + 63) / 64, TOK / 64), 256, 0, stream>>>(
        hbuf, w1 + (size_t)l * DIM * INNER2, nullptr, h1buf, TOK, INNER2, DIM, 1.0f);
    // conv + glu
    convglu_kernel<<<(TOK * INNER + 255) / 256, 256, 0, stream>>>(
        h1buf, convw + (size_t)l * INNER2 * 3, gbuf);
    // LN2 (in place)
    ln_kernel<<<TOK, 256, 0, stream>>>(gbuf, ln2_g + l * INNER, gbuf, INNER);
    // x = g@w2 + x
    gemm_kernel<true><<<dim3(DIM / 64, TOK / 64), 256, 0, stream>>>(
        gbuf, w2 + (size_t)l * INNER * DIM, xbuf, xbuf, TOK, DIM, INNER, 1.0f);
  }
  ln_kernel<<<TOK, 256, 0, stream>>>(xbuf, final_g, out, DIM);
}

// Round 2
// 2793.138 us; speedup vs baseline: 4.1555x; 4.1555x over previous
//
#include <hip/hip_runtime.h>
#include <math.h>

#define DEPTH 6
#define DIM 1024
#define HEADS 16
#define DH 64
#define INNER 2730
#define INNER2 5460
#define INNERP 2752      // INNER padded to 64-mult (K of w2 gemm)
#define N1P 5504         // INNER2 padded to 128-mult (N of w1 gemm)
#define BATCH 2
#define SEQ 1024
#define TOK (BATCH*SEQ)

typedef unsigned short ushort;
typedef __attribute__((ext_vector_type(8))) short short8;
typedef __attribute__((ext_vector_type(4))) float floatx4;

__device__ inline ushort f2bf(float f) {
  unsigned int u = __float_as_uint(f);
  u += 0x7FFF + ((u >> 16) & 1);
  return (ushort)(u >> 16);
}

template <typename T> __device__ inline T cvt_store(float v);
template <> __device__ inline float cvt_store<float>(float v) { return v; }
template <> __device__ inline ushort cvt_store<ushort>(float v) { return f2bf(v); }

__device__ inline void gload_lds16(const ushort* g, ushort* l) {
  __builtin_amdgcn_global_load_lds(
      (const __attribute__((address_space(1))) unsigned int*)g,
      (__attribute__((address_space(3))) unsigned int*)l, 16, 0, 0);
}

// ---------------- copy ----------------
__global__ void copy_kernel(float* __restrict__ dst, const float* __restrict__ src, int n) {
  int i = blockIdx.x * blockDim.x + threadIdx.x;
  if (i < n) dst[i] = src[i];
}

// ---------------- rel-pos bias table ----------------
__global__ void bias_kernel(const float* __restrict__ rel_emb, float* __restrict__ bias_t) {
  int d = blockIdx.x * blockDim.x + threadIdx.x;
  if (d >= SEQ) return;
  int bucket;
  if (d < 16) {
    bucket = d;
  } else {
    float nf = (float)d;
    int vl = 16 + (int)(logf(nf / 16.0f) / 2.0794415416798357f * 16.0f);
    bucket = vl < 31 ? vl : 31;
  }
  for (int h = 0; h < HEADS; h++)
    bias_t[h * SEQ + d] = rel_emb[bucket * HEADS + h];
}

// ---------------- weight transpose + fp32->bf16: W[K x N] -> Wt[Np x Kp] ----------------
__global__ __launch_bounds__(256) void transpose_kernel(const float* __restrict__ W,
                                                        ushort* __restrict__ Wt,
                                                        int K, int N, int Kp, int Np) {
  __shared__ float t[64][65];
  int tid = threadIdx.x;
  int k0 = blockIdx.y * 64, n0 = blockIdx.x * 64;
#pragma unroll 4
  for (int i = 0; i < 16; i++) {
    int r = (tid >> 6) + i * 4, c = tid & 63;
    int gk = k0 + r, gn = n0 + c;
    t[r][c] = (gk < K && gn < N) ? W[(size_t)gk * N + gn] : 0.f;
  }
  __syncthreads();
#pragma unroll 4
  for (int i = 0; i < 16; i++) {
    int r = (tid >> 6) + i * 4, c = tid & 63;   // out row n0+r, col k0+c
    int gn = n0 + r, gk = k0 + c;
    if (gn < Np && gk < Kp) Wt[(size_t)gn * Kp + gk] = f2bf(t[c][r]);
  }
}

// ---------------- LayerNorm, templated output (fp32 or bf16), with zero-padded cols ----------------
template <typename OutT>
__global__ __launch_bounds__(256) void ln_kernel(const float* __restrict__ in,
                                                 const float* __restrict__ g,
                                                 OutT* __restrict__ out, int cols, int ostride) {
  int row = blockIdx.x;
  const float* rp = in + (size_t)row * cols;
  float s = 0.f, ss = 0.f;
  for (int c = threadIdx.x; c < cols; c += 256) {
    float v = rp[c];
    s += v; ss += v * v;
  }
#pragma unroll
  for (int off = 32; off; off >>= 1) {
    s  += __shfl_down(s, off, 64);
    ss += __shfl_down(ss, off, 64);
  }
  __shared__ float l1[4], l2[4];
  int wid = threadIdx.x >> 6, lane = threadIdx.x & 63;
  if (lane == 0) { l1[wid] = s; l2[wid] = ss; }
  __syncthreads();
  if (threadIdx.x == 0) {
    float a = l1[0] + l1[1] + l1[2] + l1[3];
    float b = l2[0] + l2[1] + l2[2] + l2[3];
    float m = a / cols;
    float v = b / cols - m * m;
    l1[0] = m;
    l2[0] = rsqrtf(v + 1e-5f);
  }
  __syncthreads();
  float m = l1[0], r = l2[0];
  OutT* op = out + (size_t)row * ostride;
  for (int c = threadIdx.x; c < cols; c += 256)
    op[c] = cvt_store<OutT>((rp[c] - m) * r * g[c]);
  for (int c = cols + threadIdx.x; c < ostride; c += 256)
    op[c] = (OutT)0;
}

// ---------------- bf16 MFMA GEMM: C[M x N] = scale*(A @ Bt^T) (+ Cin) ----------------
// A [M x K] bf16 row-major, Bt [N x K] bf16 row-major. 128x128 tile, BK=64.
template <bool ADD>
__global__ __launch_bounds__(256) void gemm_mfma(const ushort* __restrict__ A,
                                                 const ushort* __restrict__ Bt,
                                                 const float* __restrict__ Cin,
                                                 float* __restrict__ C,
                                                 int N, int K, float scale) {
  __shared__ ushort Als[128 * 64];
  __shared__ ushort Bls[128 * 64];
  int tid = threadIdx.x;
  int w = tid >> 6, lane = tid & 63;
  int wr = w >> 1, wc = w & 1;
  size_t row0 = (size_t)blockIdx.y * 128, col0 = (size_t)blockIdx.x * 128;

  const ushort* Ag = A + (row0 + w * 32 + (lane >> 3)) * (size_t)K + (lane & 7) * 8;
  const ushort* Bg = Bt + (col0 + w * 32 + (lane >> 3)) * (size_t)K + (lane & 7) * 8;
  ushort* Al = Als + w * 32 * 64;  // wave-uniform LDS base; HW scatters lane*16B
  ushort* Bl = Bls + w * 32 * 64;

  floatx4 acc[4][4];
#pragma unroll
  for (int i = 0; i < 4; i++)
#pragma unroll
    for (int j = 0; j < 4; j++) { floatx4 z = {0.f, 0.f, 0.f, 0.f}; acc[i][j] = z; }

  int mrow = lane & 15, kq = (lane >> 4) * 8;
  for (int k0 = 0; k0 < K; k0 += 64) {
#pragma unroll
    for (int r = 0; r < 4; r++) {
      gload_lds16(Ag + (size_t)(r * 8) * K + k0, Al + r * 8 * 64);
      gload_lds16(Bg + (size_t)(r * 8) * K + k0, Bl + r * 8 * 64);
    }
    __syncthreads();
#pragma unroll
    for (int kk = 0; kk < 64; kk += 32) {
      short8 a[4], b[4];
#pragma unroll
      for (int i = 0; i < 4; i++)
        a[i] = *(const short8*)&Als[(wr * 64 + i * 16 + mrow) * 64 + kk + kq];
#pragma unroll
      for (int j = 0; j < 4; j++)
        b[j] = *(const short8*)&Bls[(wc * 64 + j * 16 + mrow) * 64 + kk + kq];
#pragma unroll
      for (int i = 0; i < 4; i++)
#pragma unroll
        for (int j = 0; j < 4; j++)
          acc[i][j] = __builtin_amdgcn_mfma_f32_16x16x32_bf16(a[i], b[j], acc[i][j], 0, 0, 0);
    }
    __syncthreads();
  }
  int orow = (lane >> 4) * 4, ocol = lane & 15;
#pragma unroll
  for (int i = 0; i < 4; i++) {
#pragma unroll
    for (int ii = 0; ii < 4; ii++) {
      size_t gr = row0 + wr * 64 + i * 16 + orow + ii;
#pragma unroll
      for (int j = 0; j < 4; j++) {
        size_t gc = col0 + wc * 64 + j * 16 + ocol;
        float v = acc[i][j][ii] * scale;
        if (ADD) v += Cin[gr * N + gc];
        C[gr * N + gc] = v;
      }
    }
  }
}

// ---------------- causal conv(3) + GLU(gelu exact) ----------------
__global__ void convglu_kernel(const float* __restrict__ h1, const float* __restrict__ cw,
                               float* __restrict__ out) {
  int idx = blockIdx.x * blockDim.x + threadIdx.x;
  const int total = TOK * INNER;
  if (idx >= total) return;
  int c = idx % INNER;
  int t = idx / INNER;
  int n = t % SEQ;
  const float* base = h1 + (size_t)t * N1P;
  float a0 = (n >= 2) ? base[c - 2 * N1P] : 0.f;
  float a1 = (n >= 1) ? base[c - N1P] : 0.f;
  float a2 = base[c];
  int cg = c + INNER;
  float g0 = (n >= 2) ? base[cg - 2 * N1P] : 0.f;
  float g1 = (n >= 1) ? base[cg - N1P] : 0.f;
  float g2 = base[cg];
  float av = a0 * cw[c * 3] + a1 * cw[c * 3 + 1] + a2 * cw[c * 3 + 2];
  float gv = g0 * cw[cg * 3] + g1 * cw[cg * 3 + 1] + g2 * cw[cg * 3 + 2];
  float gl = 0.5f * gv * (1.0f + erff(gv * 0.70710678118654752f));
  out[idx] = gl * av;
}

// ---------------- attention v2: float4 LDS, transposed V, parallel softmax, bf16 out ----------------
__global__ __launch_bounds__(256) void attn_kernel(const float* __restrict__ q,
                                                   const float* __restrict__ kv,
                                                   const float* __restrict__ bias_t,
                                                   ushort* __restrict__ o) {
  __shared__ float Qs[64 * 68];
  __shared__ float KVs[64 * 68];   // K as [pos][d]; later V^T as [d][pos] (stride 68)
  __shared__ float Ss[64 * 68];
  __shared__ float mrow[64], lrow[64], arow[64];
  int bh = blockIdx.x;
  int b = bh >> 4, h = bh & 15;
  int qt = blockIdx.y;
  int tid = threadIdx.x;
  int tx = tid & 15, ty = tid >> 4;

  {
    const float* qb = q + ((size_t)(b * SEQ + qt * 64)) * 1024 + h * 64;
    for (int i = tid; i < 64 * 16; i += 256) {
      int r = i >> 4, d4 = (i & 15) * 4;
      *(floatx4*)&Qs[r * 68 + d4] = *(const floatx4*)&qb[(size_t)r * 1024 + d4];
    }
  }
  if (tid < 64) { mrow[tid] = -1e30f; lrow[tid] = 0.f; }
  float acc[4][4] = {};
  __syncthreads();

  for (int kc = 0; kc <= qt; kc++) {
    const float* kb = kv + ((size_t)(b * SEQ + kc * 64)) * 128;
    for (int i = tid; i < 64 * 16; i += 256) {
      int r = i >> 4, d4 = (i & 15) * 4;
      *(floatx4*)&KVs[r * 68 + d4] = *(const floatx4*)&kb[(size_t)r * 128 + d4];
    }
    __syncthreads();
    // S = Q @ K^T
    float s[4][4] = {};
#pragma unroll 4
    for (int d0 = 0; d0 < 64; d0 += 4) {
      floatx4 a4[4], b4[4];
#pragma unroll
      for (int i = 0; i < 4; i++) a4[i] = *(const floatx4*)&Qs[(ty + 16 * i) * 68 + d0];
#pragma unroll
      for (int j = 0; j < 4; j++) b4[j] = *(const floatx4*)&KVs[(tx + 16 * j) * 68 + d0];
#pragma unroll
      for (int i = 0; i < 4; i++)
#pragma unroll
        for (int j = 0; j < 4; j++)
#pragma unroll
          for (int e = 0; e < 4; e++) s[i][j] += a4[i][e] * b4[j][e];
    }
#pragma unroll
    for (int i = 0; i < 4; i++) {
      int qi = qt * 64 + ty + 16 * i;
#pragma unroll
      for (int j = 0; j < 4; j++) {
        int kj = kc * 64 + tx + 16 * j;
        Ss[(ty + 16 * i) * 68 + tx + 16 * j] =
            (kj > qi) ? -1e30f : s[i][j] + bias_t[h * SEQ + (qi - kj)];
      }
    }
    __syncthreads();
    // V^T into KVs (K dead); softmax in parallel (4 threads per row)
    for (int i = tid; i < 64 * 16; i += 256) {
      int r = i >> 4, d4 = (i & 15) * 4;
      floatx4 vv = *(const floatx4*)&kb[(size_t)r * 128 + 64 + d4];
#pragma unroll
      for (int e = 0; e < 4; e++) KVs[(d4 + e) * 68 + r] = vv[e];
    }
    {
      int r = tid >> 2, p = tid & 3;
      float* srow = &Ss[r * 68 + p * 16];
      float cm = -1e30f;
#pragma unroll
      for (int c = 0; c < 16; c++) cm = fmaxf(cm, srow[c]);
      cm = fmaxf(cm, __shfl_xor(cm, 1, 64));
      cm = fmaxf(cm, __shfl_xor(cm, 2, 64));
      float m = mrow[r];
      float nm = fmaxf(m, cm);
      float sum = 0.f;
#pragma unroll
      for (int c = 0; c < 16; c++) {
        float pp = __expf(srow[c] - nm);
        srow[c] = pp;
        sum += pp;
      }
      sum += __shfl_xor(sum, 1, 64);
      sum += __shfl_xor(sum, 2, 64);
      if (p == 0) {
        float alpha = __expf(m - nm);
        mrow[r] = nm;
        lrow[r] = lrow[r] * alpha + sum;
        arow[r] = alpha;
      }
    }
    __syncthreads();
    // O = O*alpha + P @ V
#pragma unroll
    for (int i = 0; i < 4; i++) {
      float al = arow[ty + 16 * i];
#pragma unroll
      for (int j = 0; j < 4; j++) acc[i][j] *= al;
    }
#pragma unroll 4
    for (int c0 = 0; c0 < 64; c0 += 4) {
      floatx4 p4[4], v4[4];
#pragma unroll
      for (int i = 0; i < 4; i++) p4[i] = *(const floatx4*)&Ss[(ty + 16 * i) * 68 + c0];
#pragma unroll
      for (int j = 0; j < 4; j++) v4[j] = *(const floatx4*)&KVs[(tx + 16 * j) * 68 + c0];
#pragma unroll
      for (int i = 0; i < 4; i++)
#pragma unroll
        for (int j = 0; j < 4; j++)
#pragma unroll
          for (int e = 0; e < 4; e++) acc[i][j] += p4[i][e] * v4[j][e];
    }
    __syncthreads();
  }

#pragma unroll
  for (int i = 0; i < 4; i++) {
    int r = ty + 16 * i;
    float inv = 1.0f / lrow[r];
    size_t base = ((size_t)(b * SEQ + qt * 64 + r)) * 1024 + h * 64;
#pragma unroll
    for (int j = 0; j < 4; j++)
      o[base + tx + 16 * j] = f2bf(acc[i][j] * inv);
  }
}

// ---------------- launch ----------------
extern "C" void kernel_launch(void* const* d_in, const int* in_sizes, int n_in,
                              void* d_out, int out_size, void* d_ws, size_t ws_size,
                              hipStream_t stream) {
  const float* x_in    = (const float*)d_in[0];
  const float* rel_emb = (const float*)d_in[1];
  const float* qn_g    = (const float*)d_in[2];
  const float* wq      = (const float*)d_in[3];
  const float* wkv     = (const float*)d_in[4];
  const float* wo      = (const float*)d_in[5];
  const float* ln1_g   = (const float*)d_in[6];
  const float* w1      = (const float*)d_in[7];
  const float* convw   = (const float*)d_in[8];
  const float* ln2_g   = (const float*)d_in[9];
  const float* w2      = (const float*)d_in[10];
  const float* final_g = (const float*)d_in[11];
  float* out = (float*)d_out;

  // workspace layout (floats), liveness-aliased, total ~98.5 MB
  float* ws = (float*)d_ws;
  float* xbuf  = ws;                        // 2,097,152 f  (residual, always live)
  float* h1buf = xbuf + (size_t)TOK * DIM;  // 11,272,192 f (2048 x 5504)
  float* qbuf  = h1buf;                     // alias: live gemm-q .. attn
  float* kvbuf = h1buf + (size_t)TOK * DIM; // alias: live gemm-kv .. attn
  float* cbuf  = h1buf + (size_t)TOK * N1P; // 5,591,040 f (2048 x 2730)
  ushort* obuf = (ushort*)cbuf;             // alias: live attn .. gemm-wo
  ushort* hbuf = (ushort*)cbuf;             // alias: live ln .. gemm (disjoint from obuf)
  ushort* gbuf = (ushort*)(cbuf + (size_t)TOK * INNER);       // 5,636,096 us (2048 x 2752)
  ushort* wtbuf = gbuf + (size_t)TOK * INNERP;                // 5,636,096 us (max weight)
  float* bias_t = (float*)(wtbuf + (size_t)N1P * DIM);        // 16,384 f

  copy_kernel<<<(TOK * DIM + 255) / 256, 256, 0, stream>>>(xbuf, x_in, TOK * DIM);
  bias_kernel<<<4, 256, 0, stream>>>(rel_emb, bias_t);

  for (int l = 0; l < DEPTH; l++) {
    // h = LN(x, qn_g) -> bf16
    ln_kernel<ushort><<<TOK, 256, 0, stream>>>(xbuf, qn_g + l * DIM, hbuf, DIM, DIM);
    // q = h@wq * scale
    transpose_kernel<<<dim3(16, 16), 256, 0, stream>>>(wq + (size_t)l * DIM * DIM, wtbuf, DIM, DIM, DIM, DIM);
    gemm_mfma<false><<<dim3(8, 16), 256, 0, stream>>>(hbuf, wtbuf, nullptr, qbuf, DIM, DIM, 0.125f);
    // kv = h@wkv
    transpose_kernel<<<dim3(2, 16), 256, 0, stream>>>(wkv + (size_t)l * DIM * 128, wtbuf, DIM, 128, DIM, 128);
    gemm_mfma<false><<<dim3(1, 16), 256, 0, stream>>>(hbuf, wtbuf, nullptr, kvbuf, 128, DIM, 1.0f);
    // attention -> bf16 obuf
    attn_kernel<<<dim3(BATCH * HEADS, SEQ / 64), 256, 0, stream>>>(qbuf, kvbuf, bias_t, obuf);
    // x = o@wo + x
    transpose_kernel<<<dim3(16, 16), 256, 0, stream>>>(wo + (size_t)l * DIM * DIM, wtbuf, DIM, DIM, DIM, DIM);
    gemm_mfma<true><<<dim3(8, 16), 256, 0, stream>>>(obuf, wtbuf, xbuf, xbuf, DIM, DIM, 1.0f);
    // h = LN(x, ln1_g) -> bf16
    ln_kernel<ushort><<<TOK, 256, 0, stream>>>(xbuf, ln1_g + l * DIM, hbuf, DIM, DIM);
    // h1 = h@w1  (N padded 5460->5504)
    transpose_kernel<<<dim3(86, 16), 256, 0, stream>>>(w1 + (size_t)l * DIM * INNER2, wtbuf, DIM, INNER2, DIM, N1P);
    gemm_mfma<false><<<dim3(43, 16), 256, 0, stream>>>(hbuf, wtbuf, nullptr, h1buf, N1P, DIM, 1.0f);
    // conv + glu -> cbuf fp32
    convglu_kernel<<<(TOK * INNER + 255) / 256, 256, 0, stream>>>(
        h1buf, convw + (size_t)l * INNER2 * 3, cbuf);
    // LN2 -> gbuf bf16 (zero-padded to 2752)
    ln_kernel<ushort><<<TOK, 256, 0, stream>>>(cbuf, ln2_g + l * INNER, gbuf, INNER, INNERP);
    // x = g@w2 + x  (K padded 2730->2752)
    transpose_kernel<<<dim3(16, 43), 256, 0, stream>>>(w2 + (size_t)l * INNER * DIM, wtbuf, INNER, DIM, INNERP, DIM);
    gemm_mfma<true><<<dim3(8, 16), 256, 0, stream>>>(gbuf, wtbuf, xbuf, xbuf, DIM, INNERP, 1.0f);
  }
  ln_kernel<float><<<TOK, 256, 0, stream>>>(xbuf, final_g, out, DIM, DIM);
}

// Round 3
// 1961.812 us; speedup vs baseline: 5.9164x; 1.4238x over previous
//
#include <hip/hip_runtime.h>
#include <math.h>

#define DEPTH 6
#define DIM 1024
#define HEADS 16
#define DH 64
#define INNER 2730
#define INNER2 5460
#define INNERP 2752      // INNER padded to 64
#define N1P 5504         // INNER2 padded to 128
#define BATCH 2
#define SEQ 1024
#define TOK (BATCH*SEQ)
#define QKVW 1152        // 1024 q + 64 k + 64 v

typedef unsigned short ushort;
typedef __attribute__((ext_vector_type(8))) short short8;
typedef __attribute__((ext_vector_type(4))) short short4v;
typedef __attribute__((ext_vector_type(4))) float floatx4;

__device__ inline ushort f2bf(float f) {
  unsigned int u = __float_as_uint(f);
  u += 0x7FFF + ((u >> 16) & 1);
  return (ushort)(u >> 16);
}
__device__ inline float bf2f(ushort u) {
  return __uint_as_float(((unsigned int)u) << 16);
}

template <typename T> __device__ inline T cvt_store(float v);
template <> __device__ inline float cvt_store<float>(float v) { return v; }
template <> __device__ inline ushort cvt_store<ushort>(float v) { return f2bf(v); }

__device__ inline void gload_lds16(const ushort* g, ushort* l) {
  __builtin_amdgcn_global_load_lds(
      (const __attribute__((address_space(1))) unsigned int*)g,
      (__attribute__((address_space(3))) unsigned int*)l, 16, 0, 0);
}

// ---------------- copy ----------------
__global__ void copy_kernel(float* __restrict__ dst, const float* __restrict__ src, int n) {
  int i = blockIdx.x * blockDim.x + threadIdx.x;
  if (i < n) dst[i] = src[i];
}

// ---------------- bias fragment table ----------------
// bias_c[h][dq][rowgrp(16)][j(4)][col(16)][reg(4)]  (4096 floats per (h,dq))
// value = rel_emb[bucket(dq*64 + row - colg)][h], row=rowgrp*4+reg, colg=j*16+col
__global__ void bias_frag_kernel(const float* __restrict__ rel_emb, float* __restrict__ bias_c) {
  int h = blockIdx.x >> 4, dq = blockIdx.x & 15;
  for (int i = threadIdx.x; i < 4096; i += 256) {
    int reg = i & 3, col = (i >> 2) & 15, j = (i >> 6) & 3, rowgrp = i >> 8;
    int row = rowgrp * 4 + reg, colg = j * 16 + col;
    int d = dq * 64 + row - colg;
    d = d < 0 ? 0 : (d > 1023 ? 1023 : d);
    int bucket;
    if (d < 16) {
      bucket = d;
    } else {
      float nf = (float)d;
      int vl = 16 + (int)(logf(nf / 16.0f) / 2.0794415416798357f * 16.0f);
      bucket = vl < 31 ? vl : 31;
    }
    bias_c[((size_t)(h * 16 + dq)) * 4096 + i] = rel_emb[bucket * HEADS + h];
  }
}

// ---------------- weight transpose + scale + fp32->bf16: W[K x N] -> Wt[Np x Kp] ----------------
__global__ __launch_bounds__(256) void transpose_kernel(const float* __restrict__ W,
                                                        ushort* __restrict__ Wt,
                                                        int K, int N, int Kp, int Np,
                                                        float scale) {
  __shared__ float t[64][65];
  int tid = threadIdx.x;
  int k0 = blockIdx.y * 64, n0 = blockIdx.x * 64;
#pragma unroll 4
  for (int i = 0; i < 16; i++) {
    int r = (tid >> 6) + i * 4, c = tid & 63;
    int gk = k0 + r, gn = n0 + c;
    t[r][c] = (gk < K && gn < N) ? W[(size_t)gk * N + gn] * scale : 0.f;
  }
  __syncthreads();
#pragma unroll 4
  for (int i = 0; i < 16; i++) {
    int r = (tid >> 6) + i * 4, c = tid & 63;
    int gn = n0 + r, gk = k0 + c;
    if (gn < Np && gk < Kp) Wt[(size_t)gn * Kp + gk] = f2bf(t[c][r]);
  }
}

// ---------------- LayerNorm ----------------
template <typename OutT>
__global__ __launch_bounds__(256) void ln_kernel(const float* __restrict__ in,
                                                 const float* __restrict__ g,
                                                 OutT* __restrict__ out, int cols, int ostride) {
  int row = blockIdx.x;
  const float* rp = in + (size_t)row * cols;
  float s = 0.f, ss = 0.f;
  for (int c = threadIdx.x; c < cols; c += 256) {
    float v = rp[c];
    s += v; ss += v * v;
  }
#pragma unroll
  for (int off = 32; off; off >>= 1) {
    s  += __shfl_down(s, off, 64);
    ss += __shfl_down(ss, off, 64);
  }
  __shared__ float l1[4], l2[4];
  int wid = threadIdx.x >> 6, lane = threadIdx.x & 63;
  if (lane == 0) { l1[wid] = s; l2[wid] = ss; }
  __syncthreads();
  if (threadIdx.x == 0) {
    float a = l1[0] + l1[1] + l1[2] + l1[3];
    float bb = l2[0] + l2[1] + l2[2] + l2[3];
    float m = a / cols;
    float v = bb / cols - m * m;
    l1[0] = m;
    l2[0] = rsqrtf(v + 1e-5f);
  }
  __syncthreads();
  float m = l1[0], r = l2[0];
  OutT* op = out + (size_t)row * ostride;
  for (int c = threadIdx.x; c < cols; c += 256)
    op[c] = cvt_store<OutT>((rp[c] - m) * r * g[c]);
  for (int c = cols + threadIdx.x; c < ostride; c += 256)
    op[c] = (OutT)0;
}

// ---------------- bf16 MFMA GEMM, 128x128 tile ----------------
template <bool ADD, typename OutT>
__global__ __launch_bounds__(256) void gemm_mfma128(const ushort* __restrict__ A,
                                                    const ushort* __restrict__ Bt,
                                                    const float* __restrict__ Cin,
                                                    OutT* __restrict__ C,
                                                    int N, int K, float scale) {
  __shared__ ushort Als[128 * 64];
  __shared__ ushort Bls[128 * 64];
  int tid = threadIdx.x;
  int w = tid >> 6, lane = tid & 63;
  int wr = w >> 1, wc = w & 1;
  size_t row0 = (size_t)blockIdx.y * 128, col0 = (size_t)blockIdx.x * 128;

  const ushort* Ag = A + (row0 + w * 32 + (lane >> 3)) * (size_t)K + (lane & 7) * 8;
  const ushort* Bg = Bt + (col0 + w * 32 + (lane >> 3)) * (size_t)K + (lane & 7) * 8;
  ushort* Al = Als + w * 32 * 64;
  ushort* Bl = Bls + w * 32 * 64;

  floatx4 acc[4][4];
#pragma unroll
  for (int i = 0; i < 4; i++)
#pragma unroll
    for (int j = 0; j < 4; j++) { floatx4 z = {0.f, 0.f, 0.f, 0.f}; acc[i][j] = z; }

  int mrow = lane & 15, kq = (lane >> 4) * 8;
  for (int k0 = 0; k0 < K; k0 += 64) {
#pragma unroll
    for (int r = 0; r < 4; r++) {
      gload_lds16(Ag + (size_t)(r * 8) * K + k0, Al + r * 8 * 64);
      gload_lds16(Bg + (size_t)(r * 8) * K + k0, Bl + r * 8 * 64);
    }
    __syncthreads();
#pragma unroll
    for (int kk = 0; kk < 64; kk += 32) {
      short8 a[4], b[4];
#pragma unroll
      for (int i = 0; i < 4; i++)
        a[i] = *(const short8*)&Als[(wr * 64 + i * 16 + mrow) * 64 + kk + kq];
#pragma unroll
      for (int j = 0; j < 4; j++)
        b[j] = *(const short8*)&Bls[(wc * 64 + j * 16 + mrow) * 64 + kk + kq];
#pragma unroll
      for (int i = 0; i < 4; i++)
#pragma unroll
        for (int j = 0; j < 4; j++)
          acc[i][j] = __builtin_amdgcn_mfma_f32_16x16x32_bf16(a[i], b[j], acc[i][j], 0, 0, 0);
    }
    __syncthreads();
  }
  int orow = (lane >> 4) * 4, ocol = lane & 15;
#pragma unroll
  for (int i = 0; i < 4; i++) {
#pragma unroll
    for (int ii = 0; ii < 4; ii++) {
      size_t gr = row0 + wr * 64 + i * 16 + orow + ii;
#pragma unroll
      for (int j = 0; j < 4; j++) {
        size_t gc = col0 + wc * 64 + j * 16 + ocol;
        float v = acc[i][j][ii] * scale;
        if (ADD) v += Cin[gr * N + gc];
        C[gr * N + gc] = cvt_store<OutT>(v);
      }
    }
  }
}

// ---------------- bf16 MFMA GEMM, 128x64 tile (better grid coverage for small N) ----------------
template <bool ADD, typename OutT>
__global__ __launch_bounds__(256) void gemm_mfma64(const ushort* __restrict__ A,
                                                   const ushort* __restrict__ Bt,
                                                   const float* __restrict__ Cin,
                                                   OutT* __restrict__ C,
                                                   int N, int K, float scale) {
  __shared__ ushort Als[128 * 64];
  __shared__ ushort Bls[64 * 64];
  int tid = threadIdx.x;
  int w = tid >> 6, lane = tid & 63;
  size_t row0 = (size_t)blockIdx.y * 128, col0 = (size_t)blockIdx.x * 64;

  const ushort* Ag = A + (row0 + w * 32 + (lane >> 3)) * (size_t)K + (lane & 7) * 8;
  const ushort* Bg = Bt + (col0 + w * 16 + (lane >> 3)) * (size_t)K + (lane & 7) * 8;
  ushort* Al = Als + w * 32 * 64;
  ushort* Bl = Bls + w * 16 * 64;

  floatx4 acc[2][4];
#pragma unroll
  for (int i = 0; i < 2; i++)
#pragma unroll
    for (int j = 0; j < 4; j++) { floatx4 z = {0.f, 0.f, 0.f, 0.f}; acc[i][j] = z; }

  int mrow = lane & 15, kq = (lane >> 4) * 8;
  for (int k0 = 0; k0 < K; k0 += 64) {
#pragma unroll
    for (int r = 0; r < 4; r++)
      gload_lds16(Ag + (size_t)(r * 8) * K + k0, Al + r * 8 * 64);
#pragma unroll
    for (int r = 0; r < 2; r++)
      gload_lds16(Bg + (size_t)(r * 8) * K + k0, Bl + r * 8 * 64);
    __syncthreads();
#pragma unroll
    for (int kk = 0; kk < 64; kk += 32) {
      short8 a[2], b[4];
#pragma unroll
      for (int i = 0; i < 2; i++)
        a[i] = *(const short8*)&Als[(w * 32 + i * 16 + mrow) * 64 + kk + kq];
#pragma unroll
      for (int j = 0; j < 4; j++)
        b[j] = *(const short8*)&Bls[(j * 16 + mrow) * 64 + kk + kq];
#pragma unroll
      for (int i = 0; i < 2; i++)
#pragma unroll
        for (int j = 0; j < 4; j++)
          acc[i][j] = __builtin_amdgcn_mfma_f32_16x16x32_bf16(a[i], b[j], acc[i][j], 0, 0, 0);
    }
    __syncthreads();
  }
  int orow = (lane >> 4) * 4, ocol = lane & 15;
#pragma unroll
  for (int i = 0; i < 2; i++) {
#pragma unroll
    for (int ii = 0; ii < 4; ii++) {
      size_t gr = row0 + w * 32 + i * 16 + orow + ii;
#pragma unroll
      for (int j = 0; j < 4; j++) {
        size_t gc = col0 + j * 16 + ocol;
        float v = acc[i][j][ii] * scale;
        if (ADD) v += Cin[gr * N + gc];
        C[gr * N + gc] = cvt_store<OutT>(v);
      }
    }
  }
}

// ---------------- causal conv(3) + GLU(gelu exact), bf16 input ----------------
__global__ void convglu_kernel(const ushort* __restrict__ h1, const float* __restrict__ cw,
                               float* __restrict__ out) {
  int idx = blockIdx.x * blockDim.x + threadIdx.x;
  const int total = TOK * INNER;
  if (idx >= total) return;
  int c = idx % INNER;
  int t = idx / INNER;
  int n = t % SEQ;
  const ushort* base = h1 + (size_t)t * N1P;
  float a0 = (n >= 2) ? bf2f(base[c - 2 * N1P]) : 0.f;
  float a1 = (n >= 1) ? bf2f(base[c - N1P]) : 0.f;
  float a2 = bf2f(base[c]);
  int cg = c + INNER;
  float g0 = (n >= 2) ? bf2f(base[cg - 2 * N1P]) : 0.f;
  float g1 = (n >= 1) ? bf2f(base[cg - N1P]) : 0.f;
  float g2 = bf2f(base[cg]);
  float av = a0 * cw[c * 3] + a1 * cw[c * 3 + 1] + a2 * cw[c * 3 + 2];
  float gv = g0 * cw[cg * 3] + g1 * cw[cg * 3 + 1] + g2 * cw[cg * 3 + 2];
  float gl = 0.5f * gv * (1.0f + erff(gv * 0.70710678118654752f));
  out[idx] = gl * av;
}

// ---------------- MFMA flash attention ----------------
// qkv: [TOK][1152] bf16 (q cols 0..1023 pre-scaled, k 1024..1087, v 1088..1151)
// grid (32 bh, 16 tiles-permuted), block 256 (4 waves, 16 q-rows each)
__global__ __launch_bounds__(256) void attn_mfma(const ushort* __restrict__ qkv,
                                                 const float* __restrict__ bias_c,
                                                 ushort* __restrict__ o) {
  __shared__ ushort Ks[64 * 72];   // [key][k]
  __shared__ ushort Vt[64 * 72];   // [dh][key]
  __shared__ ushort Ps[64 * 72];   // [qrow][key]
  __shared__ float arow[64];
  int tid = threadIdx.x;
  int lane = tid & 63, w = tid >> 6;
  int quad = lane >> 4, col = lane & 15;
  int b = blockIdx.x >> 4, h = blockIdx.x & 15;
  int y = blockIdx.y;
  int qt = (y < 8) ? (15 - y) : (y - 8);   // pair blocks c,c+256 to ~constant work

  // Q A-fragments in registers: rows qt*64 + w*16 + col
  const ushort* qrow = qkv + (size_t)(b * SEQ + qt * 64 + w * 16 + col) * QKVW + h * 64;
  short8 qa[2];
  qa[0] = *(const short8*)&qrow[quad * 8];
  qa[1] = *(const short8*)&qrow[32 + quad * 8];

  float m_[4], l_[4];
  floatx4 oacc[4];
#pragma unroll
  for (int r = 0; r < 4; r++) { m_[r] = -1e30f; l_[r] = 0.f; }
#pragma unroll
  for (int mt = 0; mt < 4; mt++) { floatx4 z = {0.f, 0.f, 0.f, 0.f}; oacc[mt] = z; }

  for (int kc = 0; kc <= qt; kc++) {
    // stage K [key][k] and V^T [dh][key] (lane-contiguous writes: conflict-free)
    const ushort* kvb = qkv + (size_t)(b * SEQ + kc * 64) * QKVW;
#pragma unroll
    for (int it = 0; it < 2; it++) {
      int r = lane;                 // (tid + it*256) & 63 == lane
      int c8 = w + it * 4;
      short8 kk8 = *(const short8*)&kvb[(size_t)r * QKVW + 1024 + c8 * 8];
      *(short8*)&Ks[r * 72 + c8 * 8] = kk8;
      short8 vv = *(const short8*)&kvb[(size_t)r * QKVW + 1088 + c8 * 8];
#pragma unroll
      for (int e = 0; e < 8; e++) Vt[(c8 * 8 + e) * 72 + r] = (ushort)vv[e];
    }
    __syncthreads();

    // S = Q @ K^T   (C-layout: row=quad*4+reg, col within j-tile = lane&15)
    floatx4 s[4];
#pragma unroll
    for (int j = 0; j < 4; j++) { floatx4 z = {0.f, 0.f, 0.f, 0.f}; s[j] = z; }
#pragma unroll
    for (int kk = 0; kk < 2; kk++) {
#pragma unroll
      for (int j = 0; j < 4; j++) {
        short8 kb = *(const short8*)&Ks[(j * 16 + col) * 72 + kk * 32 + quad * 8];
        s[j] = __builtin_amdgcn_mfma_f32_16x16x32_bf16(qa[kk], kb, s[j], 0, 0, 0);
      }
    }

    // bias (precomputed in fragment layout) + causal mask
    int dq = qt - kc;
    const floatx4* bc = (const floatx4*)(bias_c + ((size_t)(h * 16 + dq) * 4096 + (w * 4 + quad) * 256));
    float pv[4][4];
#pragma unroll
    for (int j = 0; j < 4; j++) {
      floatx4 bf = bc[j * 16 + col];
#pragma unroll
      for (int reg = 0; reg < 4; reg++) {
        float v = s[j][reg] + bf[reg];
        if (dq == 0 && (j * 16 + col) > (w * 16 + quad * 4 + reg)) v = -1e30f;
        pv[j][reg] = v;
      }
    }

    // online softmax (rows quad*4+reg, reduce over 16 lanes of quad group)
#pragma unroll
    for (int reg = 0; reg < 4; reg++) {
      float cm = fmaxf(fmaxf(pv[0][reg], pv[1][reg]), fmaxf(pv[2][reg], pv[3][reg]));
      cm = fmaxf(cm, __shfl_xor(cm, 1, 64));
      cm = fmaxf(cm, __shfl_xor(cm, 2, 64));
      cm = fmaxf(cm, __shfl_xor(cm, 4, 64));
      cm = fmaxf(cm, __shfl_xor(cm, 8, 64));
      float nm = fmaxf(m_[reg], cm);
      float alpha = __expf(m_[reg] - nm);
      float rs = 0.f;
#pragma unroll
      for (int j = 0; j < 4; j++) {
        float e = __expf(pv[j][reg] - nm);
        pv[j][reg] = e;
        rs += e;
      }
      rs += __shfl_xor(rs, 1, 64);
      rs += __shfl_xor(rs, 2, 64);
      rs += __shfl_xor(rs, 4, 64);
      rs += __shfl_xor(rs, 8, 64);
      l_[reg] = l_[reg] * alpha + rs;
      m_[reg] = nm;
      if (col == 0) arow[w * 16 + quad * 4 + reg] = alpha;
    }

    // P -> LDS bf16 [qrow][key]
#pragma unroll
    for (int j = 0; j < 4; j++)
#pragma unroll
      for (int reg = 0; reg < 4; reg++)
        Ps[(w * 16 + quad * 4 + reg) * 72 + j * 16 + col] = f2bf(pv[j][reg]);

    asm volatile("s_waitcnt lgkmcnt(0)" ::: "memory");
    float aval = arow[w * 16 + col];
#pragma unroll
    for (int mt = 0; mt < 4; mt++) oacc[mt] *= aval;

    // O^T += V^T @ P^T : A = Vt[dh][key], B = Ps[qrow][key]
#pragma unroll
    for (int kk = 0; kk < 2; kk++) {
      short8 pb = *(const short8*)&Ps[(w * 16 + col) * 72 + kk * 32 + quad * 8];
#pragma unroll
      for (int mt = 0; mt < 4; mt++) {
        short8 va = *(const short8*)&Vt[(mt * 16 + col) * 72 + kk * 32 + quad * 8];
        oacc[mt] = __builtin_amdgcn_mfma_f32_16x16x32_bf16(va, pb, oacc[mt], 0, 0, 0);
      }
    }
    __syncthreads();   // protect Ks/Vt for next chunk
  }

  // epilogue: divide by l (per q-row = col dim of O^T), write bf16
#pragma unroll
  for (int reg = 0; reg < 4; reg++)
    if (col == 0) arow[w * 16 + quad * 4 + reg] = 1.0f / l_[reg];
  asm volatile("s_waitcnt lgkmcnt(0)" ::: "memory");
  float lv = arow[w * 16 + col];
  size_t obase = (size_t)(b * SEQ + qt * 64 + w * 16 + col) * 1024 + h * 64;
#pragma unroll
  for (int mt = 0; mt < 4; mt++) {
    short4v pk;
#pragma unroll
    for (int reg = 0; reg < 4; reg++) pk[reg] = (short)f2bf(oacc[mt][reg] * lv);
    *(short4v*)&o[obase + mt * 16 + quad * 4] = pk;
  }
}

// ---------------- launch ----------------
extern "C" void kernel_launch(void* const* d_in, const int* in_sizes, int n_in,
                              void* d_out, int out_size, void* d_ws, size_t ws_size,
                              hipStream_t stream) {
  const float* x_in    = (const float*)d_in[0];
  const float* rel_emb = (const float*)d_in[1];
  const float* qn_g    = (const float*)d_in[2];
  const float* wq      = (const float*)d_in[3];
  const float* wkv     = (const float*)d_in[4];
  const float* wo      = (const float*)d_in[5];
  const float* ln1_g   = (const float*)d_in[6];
  const float* w1      = (const float*)d_in[7];
  const float* convw   = (const float*)d_in[8];
  const float* ln2_g   = (const float*)d_in[9];
  const float* w2      = (const float*)d_in[10];
  const float* final_g = (const float*)d_in[11];
  float* out = (float*)d_out;

  // ws layout (~78 MB)
  float* xbuf   = (float*)d_ws;                       // TOK*DIM f32
  float* cbuf   = xbuf + (size_t)TOK * DIM;           // TOK*INNER f32
  float* bias_c = cbuf + (size_t)TOK * INNER;         // 16*16*4096 f32
  ushort* h1buf = (ushort*)(bias_c + (size_t)16 * 16 * 4096);  // TOK*N1P bf16
  ushort* gbuf  = h1buf;                              // alias (h1 dead after conv)
  ushort* hbuf  = h1buf + (size_t)TOK * N1P;          // TOK*DIM bf16
  ushort* obuf  = hbuf;                               // alias (disjoint liveness)
  ushort* qkvbuf = hbuf + (size_t)TOK * DIM;          // TOK*1152 bf16
  ushort* wtbuf  = qkvbuf + (size_t)TOK * QKVW;       // N1P*DIM bf16

  copy_kernel<<<(TOK * DIM + 255) / 256, 256, 0, stream>>>(xbuf, x_in, TOK * DIM);
  bias_frag_kernel<<<256, 256, 0, stream>>>(rel_emb, bias_c);

  for (int l = 0; l < DEPTH; l++) {
    // h = LN(x, qn_g) -> bf16
    ln_kernel<ushort><<<TOK, 256, 0, stream>>>(xbuf, qn_g + l * DIM, hbuf, DIM, DIM);
    // fused qkv = h @ [wq*0.125 | wkv]
    transpose_kernel<<<dim3(16, 16), 256, 0, stream>>>(
        wq + (size_t)l * DIM * DIM, wtbuf, DIM, DIM, DIM, DIM, 0.125f);
    transpose_kernel<<<dim3(2, 16), 256, 0, stream>>>(
        wkv + (size_t)l * DIM * 128, wtbuf + (size_t)1024 * DIM, DIM, 128, DIM, 128, 1.0f);
    gemm_mfma64<false, ushort><<<dim3(18, 16), 256, 0, stream>>>(
        hbuf, wtbuf, nullptr, qkvbuf, QKVW, DIM, 1.0f);
    // attention -> bf16 obuf
    attn_mfma<<<dim3(BATCH * HEADS, 16), 256, 0, stream>>>(qkvbuf, bias_c, obuf);
    // x = o@wo + x
    transpose_kernel<<<dim3(16, 16), 256, 0, stream>>>(
        wo + (size_t)l * DIM * DIM, wtbuf, DIM, DIM, DIM, DIM, 1.0f);
    gemm_mfma64<true, float><<<dim3(16, 16), 256, 0, stream>>>(
        obuf, wtbuf, xbuf, xbuf, DIM, DIM, 1.0f);
    // h = LN(x, ln1_g) -> bf16
    ln_kernel<ushort><<<TOK, 256, 0, stream>>>(xbuf, ln1_g + l * DIM, hbuf, DIM, DIM);
    // h1 = h@w1 -> bf16 (N padded 5460->5504)
    transpose_kernel<<<dim3(86, 16), 256, 0, stream>>>(
        w1 + (size_t)l * DIM * INNER2, wtbuf, DIM, INNER2, DIM, N1P, 1.0f);
    gemm_mfma128<false, ushort><<<dim3(43, 16), 256, 0, stream>>>(
        hbuf, wtbuf, nullptr, h1buf, N1P, DIM, 1.0f);
    // conv + glu -> cbuf fp32
    convglu_kernel<<<(TOK * INNER + 255) / 256, 256, 0, stream>>>(
        h1buf, convw + (size_t)l * INNER2 * 3, cbuf);
    // LN2 -> gbuf bf16 (zero-padded to 2752)
    ln_kernel<ushort><<<TOK, 256, 0, stream>>>(cbuf, ln2_g + l * INNER, gbuf, INNER, INNERP);
    // x = g@w2 + x (K padded 2730->2752)
    transpose_kernel<<<dim3(16, 43), 256, 0, stream>>>(
        w2 + (size_t)l * INNER * DIM, wtbuf, INNER, DIM, INNERP, DIM, 1.0f);
    gemm_mfma64<true, float><<<dim3(16, 16), 256, 0, stream>>>(
        gbuf, wtbuf, xbuf, xbuf, DIM, INNERP, 1.0f);
  }
  ln_kernel<float><<<TOK, 256, 0, stream>>>(xbuf, final_g, out, DIM, DIM);
}

// Round 4
// 1637.882 us; speedup vs baseline: 7.0865x; 1.1978x over previous
//
#include <hip/hip_runtime.h>
#include <math.h>

#define DEPTH 6
#define DIM 1024
#define HEADS 16
#define DH 64
#define INNER 2730
#define INNER2 5460
#define INNERP 2752      // INNER padded to 64
#define N1P 5504         // INNER2 padded to 128
#define BATCH 2
#define SEQ 1024
#define TOK (BATCH*SEQ)
#define QKVW 1152        // 1024 q + 64 k + 64 v

typedef unsigned short ushort;
typedef __attribute__((ext_vector_type(8))) short short8;
typedef __attribute__((ext_vector_type(4))) short short4v;
typedef __attribute__((ext_vector_type(4))) unsigned short ushort4v;
typedef __attribute__((ext_vector_type(2))) unsigned short ushort2v;
typedef __attribute__((ext_vector_type(4))) float floatx4;

__device__ inline ushort f2bf(float f) {
  unsigned int u = __float_as_uint(f);
  u += 0x7FFF + ((u >> 16) & 1);
  return (ushort)(u >> 16);
}
__device__ inline float bf2f(ushort u) {
  return __uint_as_float(((unsigned int)u) << 16);
}

__device__ inline void gload_lds16(const ushort* g, ushort* l) {
  __builtin_amdgcn_global_load_lds(
      (const __attribute__((address_space(1))) unsigned int*)g,
      (__attribute__((address_space(3))) unsigned int*)l, 16, 0, 0);
}

// ---------------- copy ----------------
__global__ void copy_kernel(float* __restrict__ dst, const float* __restrict__ src, int n) {
  int i = blockIdx.x * blockDim.x + threadIdx.x;
  if (i < n) dst[i] = src[i];
}

// ---------------- bias fragment table ----------------
// bias_c[h][dq][rowgrp(16)][j(4)][col(16)][reg(4)]
__global__ void bias_frag_kernel(const float* __restrict__ rel_emb, float* __restrict__ bias_c) {
  int h = blockIdx.x >> 4, dq = blockIdx.x & 15;
  for (int i = threadIdx.x; i < 4096; i += 256) {
    int reg = i & 3, col = (i >> 2) & 15, j = (i >> 6) & 3, rowgrp = i >> 8;
    int row = rowgrp * 4 + reg, colg = j * 16 + col;
    int d = dq * 64 + row - colg;
    d = d < 0 ? 0 : (d > 1023 ? 1023 : d);
    int bucket;
    if (d < 16) {
      bucket = d;
    } else {
      float nf = (float)d;
      int vl = 16 + (int)(logf(nf / 16.0f) / 2.0794415416798357f * 16.0f);
      bucket = vl < 31 ? vl : 31;
    }
    bias_c[((size_t)(h * 16 + dq)) * 4096 + i] = rel_emb[bucket * HEADS + h];
  }
}

// ---------------- vectorized transpose + f32->bf16: W[K x N] -> Wt[Np x Kp] ----------------
// float4 reads, LDS-transposed staging t[n][k], short8 (16B) stores.
__device__ inline void transpose_body(const float* __restrict__ W, ushort* __restrict__ Wt,
                                      int K, int N, int Kp, int Np, float scale,
                                      int k0, int n0, size_t dst_row0) {
  __shared__ float t[64][65];   // t[n][k]
  int tid = threadIdx.x;
  int kl = tid >> 4, nc = (tid & 15) * 4;
#pragma unroll
  for (int it = 0; it < 4; it++) {
    int k = kl + it * 16;
    int gk = k0 + k, gn = n0 + nc;
    floatx4 v = {0.f, 0.f, 0.f, 0.f};
    if (gk < K && gn < N) v = *(const floatx4*)&W[(size_t)gk * N + gn];
    t[nc + 0][k] = v[0] * scale;
    t[nc + 1][k] = v[1] * scale;
    t[nc + 2][k] = v[2] * scale;
    t[nc + 3][k] = v[3] * scale;
  }
  __syncthreads();
  int nr = tid >> 3, q = tid & 7;
#pragma unroll
  for (int it = 0; it < 2; it++) {
    int n = nr + it * 32;
    if (n0 + n < Np) {
      short8 p;
#pragma unroll
      for (int e = 0; e < 8; e++) p[e] = (short)f2bf(t[n][q * 8 + e]);
      *(short8*)&Wt[(dst_row0 + n) * Kp + k0 + q * 8] = p;
    }
  }
}

__global__ __launch_bounds__(256) void transpose_vec(const float* __restrict__ W,
                                                     ushort* __restrict__ Wt,
                                                     int K, int N, int Kp, int Np, float scale) {
  transpose_body(W, Wt, K, N, Kp, Np, scale, blockIdx.y * 64, blockIdx.x * 64,
                 (size_t)blockIdx.x * 64);
}

// fused wq (scaled) + wkv transpose into one [1152 x 1024] buffer. grid (18,16)
__global__ __launch_bounds__(256) void transpose_qkv(const float* __restrict__ wq,
                                                     const float* __restrict__ wkv,
                                                     ushort* __restrict__ Wt) {
  int bx = blockIdx.x;
  if (bx < 16) {
    transpose_body(wq, Wt, 1024, 1024, 1024, 1024, 0.125f, blockIdx.y * 64, bx * 64,
                   (size_t)bx * 64);
  } else {
    transpose_body(wkv, Wt, 1024, 128, 1024, 128, 1.0f, blockIdx.y * 64, (bx - 16) * 64,
                   (size_t)1024 + (bx - 16) * 64);
  }
}

// ---------------- LayerNorm specialized for 1024 cols ----------------
template <typename OutT>
__global__ __launch_bounds__(256) void ln1024(const float* __restrict__ in,
                                              const float* __restrict__ g,
                                              OutT* __restrict__ out) {
  int row = blockIdx.x;
  int tid = threadIdx.x;
  floatx4 v = *(const floatx4*)&in[(size_t)row * 1024 + tid * 4];
  float s = v[0] + v[1] + v[2] + v[3];
  float ss = v[0] * v[0] + v[1] * v[1] + v[2] * v[2] + v[3] * v[3];
#pragma unroll
  for (int off = 32; off; off >>= 1) {
    s  += __shfl_down(s, off, 64);
    ss += __shfl_down(ss, off, 64);
  }
  __shared__ float l1[4], l2[4];
  int wid = tid >> 6, lane = tid & 63;
  if (lane == 0) { l1[wid] = s; l2[wid] = ss; }
  __syncthreads();
  if (tid == 0) {
    float a = l1[0] + l1[1] + l1[2] + l1[3];
    float bb = l2[0] + l2[1] + l2[2] + l2[3];
    float m = a * (1.0f / 1024.0f);
    float var = bb * (1.0f / 1024.0f) - m * m;
    l1[0] = m;
    l2[0] = rsqrtf(var + 1e-5f);
  }
  __syncthreads();
  float m = l1[0], r = l2[0];
  floatx4 gv = *(const floatx4*)&g[tid * 4];
  if constexpr (sizeof(OutT) == 2) {
    short4v p;
#pragma unroll
    for (int e = 0; e < 4; e++) p[e] = (short)f2bf((v[e] - m) * r * gv[e]);
    *(short4v*)&out[(size_t)row * 1024 + tid * 4] = p;
  } else {
    floatx4 p;
#pragma unroll
    for (int e = 0; e < 4; e++) p[e] = (v[e] - m) * r * gv[e];
    *(floatx4*)&out[(size_t)row * 1024 + tid * 4] = p;
  }
}

// ---------------- bf16 MFMA GEMM, 128x128 tile ----------------
template <bool ADD, typename OutT>
__global__ __launch_bounds__(256) void gemm_mfma128(const ushort* __restrict__ A,
                                                    const ushort* __restrict__ Bt,
                                                    const float* __restrict__ Cin,
                                                    OutT* __restrict__ C,
                                                    int N, int K, float scale) {
  __shared__ ushort Als[128 * 64];
  __shared__ ushort Bls[128 * 64];
  int tid = threadIdx.x;
  int w = tid >> 6, lane = tid & 63;
  int wr = w >> 1, wc = w & 1;
  size_t row0 = (size_t)blockIdx.y * 128, col0 = (size_t)blockIdx.x * 128;

  const ushort* Ag = A + (row0 + w * 32 + (lane >> 3)) * (size_t)K + (lane & 7) * 8;
  const ushort* Bg = Bt + (col0 + w * 32 + (lane >> 3)) * (size_t)K + (lane & 7) * 8;
  ushort* Al = Als + w * 32 * 64;
  ushort* Bl = Bls + w * 32 * 64;

  floatx4 acc[4][4];
#pragma unroll
  for (int i = 0; i < 4; i++)
#pragma unroll
    for (int j = 0; j < 4; j++) { floatx4 z = {0.f, 0.f, 0.f, 0.f}; acc[i][j] = z; }

  int mrow = lane & 15, kq = (lane >> 4) * 8;
  for (int k0 = 0; k0 < K; k0 += 64) {
#pragma unroll
    for (int r = 0; r < 4; r++) {
      gload_lds16(Ag + (size_t)(r * 8) * K + k0, Al + r * 8 * 64);
      gload_lds16(Bg + (size_t)(r * 8) * K + k0, Bl + r * 8 * 64);
    }
    __syncthreads();
#pragma unroll
    for (int kk = 0; kk < 64; kk += 32) {
      short8 a[4], b[4];
#pragma unroll
      for (int i = 0; i < 4; i++)
        a[i] = *(const short8*)&Als[(wr * 64 + i * 16 + mrow) * 64 + kk + kq];
#pragma unroll
      for (int j = 0; j < 4; j++)
        b[j] = *(const short8*)&Bls[(wc * 64 + j * 16 + mrow) * 64 + kk + kq];
#pragma unroll
      for (int i = 0; i < 4; i++)
#pragma unroll
        for (int j = 0; j < 4; j++)
          acc[i][j] = __builtin_amdgcn_mfma_f32_16x16x32_bf16(a[i], b[j], acc[i][j], 0, 0, 0);
    }
    __syncthreads();
  }
  int orow = (lane >> 4) * 4, ocol = lane & 15;
#pragma unroll
  for (int i = 0; i < 4; i++) {
#pragma unroll
    for (int ii = 0; ii < 4; ii++) {
      size_t gr = row0 + wr * 64 + i * 16 + orow + ii;
#pragma unroll
      for (int j = 0; j < 4; j++) {
        size_t gc = col0 + wc * 64 + j * 16 + ocol;
        float v = acc[i][j][ii] * scale;
        if (ADD) v += Cin[gr * N + gc];
        if constexpr (sizeof(OutT) == 2) C[gr * N + gc] = f2bf(v);
        else C[gr * N + gc] = v;
      }
    }
  }
}

// ---------------- bf16 MFMA GEMM, 128x64 tile ----------------
template <bool ADD, typename OutT>
__global__ __launch_bounds__(256) void gemm_mfma64(const ushort* __restrict__ A,
                                                   const ushort* __restrict__ Bt,
                                                   const float* __restrict__ Cin,
                                                   OutT* __restrict__ C,
                                                   int N, int K, float scale) {
  __shared__ ushort Als[128 * 64];
  __shared__ ushort Bls[64 * 64];
  int tid = threadIdx.x;
  int w = tid >> 6, lane = tid & 63;
  size_t row0 = (size_t)blockIdx.y * 128, col0 = (size_t)blockIdx.x * 64;

  const ushort* Ag = A + (row0 + w * 32 + (lane >> 3)) * (size_t)K + (lane & 7) * 8;
  const ushort* Bg = Bt + (col0 + w * 16 + (lane >> 3)) * (size_t)K + (lane & 7) * 8;
  ushort* Al = Als + w * 32 * 64;
  ushort* Bl = Bls + w * 16 * 64;

  floatx4 acc[2][4];
#pragma unroll
  for (int i = 0; i < 2; i++)
#pragma unroll
    for (int j = 0; j < 4; j++) { floatx4 z = {0.f, 0.f, 0.f, 0.f}; acc[i][j] = z; }

  int mrow = lane & 15, kq = (lane >> 4) * 8;
  for (int k0 = 0; k0 < K; k0 += 64) {
#pragma unroll
    for (int r = 0; r < 4; r++)
      gload_lds16(Ag + (size_t)(r * 8) * K + k0, Al + r * 8 * 64);
#pragma unroll
    for (int r = 0; r < 2; r++)
      gload_lds16(Bg + (size_t)(r * 8) * K + k0, Bl + r * 8 * 64);
    __syncthreads();
#pragma unroll
    for (int kk = 0; kk < 64; kk += 32) {
      short8 a[2], b[4];
#pragma unroll
      for (int i = 0; i < 2; i++)
        a[i] = *(const short8*)&Als[(w * 32 + i * 16 + mrow) * 64 + kk + kq];
#pragma unroll
      for (int j = 0; j < 4; j++)
        b[j] = *(const short8*)&Bls[(j * 16 + mrow) * 64 + kk + kq];
#pragma unroll
      for (int i = 0; i < 2; i++)
#pragma unroll
        for (int j = 0; j < 4; j++)
          acc[i][j] = __builtin_amdgcn_mfma_f32_16x16x32_bf16(a[i], b[j], acc[i][j], 0, 0, 0);
    }
    __syncthreads();
  }
  int orow = (lane >> 4) * 4, ocol = lane & 15;
#pragma unroll
  for (int i = 0; i < 2; i++) {
#pragma unroll
    for (int ii = 0; ii < 4; ii++) {
      size_t gr = row0 + w * 32 + i * 16 + orow + ii;
#pragma unroll
      for (int j = 0; j < 4; j++) {
        size_t gc = col0 + j * 16 + ocol;
        float v = acc[i][j][ii] * scale;
        if (ADD) v += Cin[gr * N + gc];
        if constexpr (sizeof(OutT) == 2) C[gr * N + gc] = f2bf(v);
        else C[gr * N + gc] = v;
      }
    }
  }
}

// ---------------- fused causal conv(3) + GLU(gelu exact) + LayerNorm -> bf16 padded ----------------
// one block per token; vals kept in registers; block-reduce mean/var over INNER.
__global__ __launch_bounds__(256) void convglu_ln(const ushort* __restrict__ h1,
                                                  const float* __restrict__ cw,
                                                  const float* __restrict__ lng,
                                                  ushort* __restrict__ out) {
  int t = blockIdx.x;
  int n = t & (SEQ - 1);
  int tid = threadIdx.x;
  const ushort* r0 = h1 + (size_t)t * N1P;
  float vals[3][4];
  float s = 0.f, ss = 0.f;
#pragma unroll
  for (int it = 0; it < 3; it++) {
    int c = (it * 256 + tid) * 4;
#pragma unroll
    for (int e = 0; e < 4; e++) vals[it][e] = 0.f;
    if (c < INNER) {
      ushort4v a2 = *(const ushort4v*)&r0[c];
      ushort4v a1 = {0, 0, 0, 0}, a0 = {0, 0, 0, 0};
      if (n >= 1) a1 = *(const ushort4v*)&r0[c - N1P];
      if (n >= 2) a0 = *(const ushort4v*)&r0[c - 2 * N1P];
      int cg = c + INNER;   // ≡ 2 mod 4 -> two 4B-aligned ushort2 loads per row
      ushort2v g2a = *(const ushort2v*)&r0[cg];
      ushort2v g2b = *(const ushort2v*)&r0[cg + 2];
      ushort2v g1a = {0, 0}, g1b = {0, 0}, g0a = {0, 0}, g0b = {0, 0};
      if (n >= 1) { g1a = *(const ushort2v*)&r0[cg - N1P]; g1b = *(const ushort2v*)&r0[cg + 2 - N1P]; }
      if (n >= 2) { g0a = *(const ushort2v*)&r0[cg - 2 * N1P]; g0b = *(const ushort2v*)&r0[cg + 2 - 2 * N1P]; }
      const floatx4* cwa = (const floatx4*)(cw + (size_t)c * 3);   // 16B-aligned (48*g bytes)
      floatx4 f0 = cwa[0], f1 = cwa[1], f2 = cwa[2];
      float wa[12] = {f0[0], f0[1], f0[2], f0[3], f1[0], f1[1], f1[2], f1[3],
                      f2[0], f2[1], f2[2], f2[3]};
#pragma unroll
      for (int e = 0; e < 4; e++) {
        int ce = c + e;
        if (ce < INNER) {
          float av = bf2f(a0[e]) * wa[e * 3] + bf2f(a1[e]) * wa[e * 3 + 1] +
                     bf2f(a2[e]) * wa[e * 3 + 2];
          int cge = ce + INNER;
          float w0g = cw[cge * 3], w1g = cw[cge * 3 + 1], w2g = cw[cge * 3 + 2];
          float g0f = bf2f(e < 2 ? g0a[e & 1] : g0b[e & 1]);
          float g1f = bf2f(e < 2 ? g1a[e & 1] : g1b[e & 1]);
          float g2f = bf2f(e < 2 ? g2a[e & 1] : g2b[e & 1]);
          float gvv = g0f * w0g + g1f * w1g + g2f * w2g;
          float gl = 0.5f * gvv * (1.0f + erff(gvv * 0.70710678118654752f));
          float val = gl * av;
          vals[it][e] = val;
          s += val;
          ss += val * val;
        }
      }
    }
  }
  // block reduction over INNER values
#pragma unroll
  for (int off = 32; off; off >>= 1) {
    s  += __shfl_down(s, off, 64);
    ss += __shfl_down(ss, off, 64);
  }
  __shared__ float l1[4], l2[4];
  int wid = tid >> 6, lane = tid & 63;
  if (lane == 0) { l1[wid] = s; l2[wid] = ss; }
  __syncthreads();
  if (tid == 0) {
    float a = l1[0] + l1[1] + l1[2] + l1[3];
    float bb = l2[0] + l2[1] + l2[2] + l2[3];
    float m = a * (1.0f / INNER);
    float var = bb * (1.0f / INNER) - m * m;
    l1[0] = m;
    l2[0] = rsqrtf(var + 1e-5f);
  }
  __syncthreads();
  float m = l1[0], r = l2[0];
#pragma unroll
  for (int it = 0; it < 3; it++) {
    int c = (it * 256 + tid) * 4;
    if (c < INNERP) {
      short4v p;
#pragma unroll
      for (int e = 0; e < 4; e++) {
        int ce = c + e;
        p[e] = (ce < INNER) ? (short)f2bf((vals[it][e] - m) * r * lng[ce]) : (short)0;
      }
      *(short4v*)&out[(size_t)t * INNERP + c] = p;
    }
  }
}

// ---------------- MFMA flash attention (unchanged from r3) ----------------
__global__ __launch_bounds__(256) void attn_mfma(const ushort* __restrict__ qkv,
                                                 const float* __restrict__ bias_c,
                                                 ushort* __restrict__ o) {
  __shared__ ushort Ks[64 * 72];
  __shared__ ushort Vt[64 * 72];
  __shared__ ushort Ps[64 * 72];
  __shared__ float arow[64];
  int tid = threadIdx.x;
  int lane = tid & 63, w = tid >> 6;
  int quad = lane >> 4, col = lane & 15;
  int b = blockIdx.x >> 4, h = blockIdx.x & 15;
  int y = blockIdx.y;
  int qt = (y < 8) ? (15 - y) : (y - 8);

  const ushort* qrow = qkv + (size_t)(b * SEQ + qt * 64 + w * 16 + col) * QKVW + h * 64;
  short8 qa[2];
  qa[0] = *(const short8*)&qrow[quad * 8];
  qa[1] = *(const short8*)&qrow[32 + quad * 8];

  float m_[4], l_[4];
  floatx4 oacc[4];
#pragma unroll
  for (int r = 0; r < 4; r++) { m_[r] = -1e30f; l_[r] = 0.f; }
#pragma unroll
  for (int mt = 0; mt < 4; mt++) { floatx4 z = {0.f, 0.f, 0.f, 0.f}; oacc[mt] = z; }

  for (int kc = 0; kc <= qt; kc++) {
    const ushort* kvb = qkv + (size_t)(b * SEQ + kc * 64) * QKVW;
#pragma unroll
    for (int it = 0; it < 2; it++) {
      int r = lane;
      int c8 = w + it * 4;
      short8 kk8 = *(const short8*)&kvb[(size_t)r * QKVW + 1024 + c8 * 8];
      *(short8*)&Ks[r * 72 + c8 * 8] = kk8;
      short8 vv = *(const short8*)&kvb[(size_t)r * QKVW + 1088 + c8 * 8];
#pragma unroll
      for (int e = 0; e < 8; e++) Vt[(c8 * 8 + e) * 72 + r] = (ushort)vv[e];
    }
    __syncthreads();

    floatx4 sarr[4];
#pragma unroll
    for (int j = 0; j < 4; j++) { floatx4 z = {0.f, 0.f, 0.f, 0.f}; sarr[j] = z; }
#pragma unroll
    for (int kk = 0; kk < 2; kk++) {
#pragma unroll
      for (int j = 0; j < 4; j++) {
        short8 kb = *(const short8*)&Ks[(j * 16 + col) * 72 + kk * 32 + quad * 8];
        sarr[j] = __builtin_amdgcn_mfma_f32_16x16x32_bf16(qa[kk], kb, sarr[j], 0, 0, 0);
      }
    }

    int dq = qt - kc;
    const floatx4* bc = (const floatx4*)(bias_c + ((size_t)(h * 16 + dq) * 4096 + (w * 4 + quad) * 256));
    float pv[4][4];
#pragma unroll
    for (int j = 0; j < 4; j++) {
      floatx4 bf = bc[j * 16 + col];
#pragma unroll
      for (int reg = 0; reg < 4; reg++) {
        float v = sarr[j][reg] + bf[reg];
        if (dq == 0 && (j * 16 + col) > (w * 16 + quad * 4 + reg)) v = -1e30f;
        pv[j][reg] = v;
      }
    }

#pragma unroll
    for (int reg = 0; reg < 4; reg++) {
      float cm = fmaxf(fmaxf(pv[0][reg], pv[1][reg]), fmaxf(pv[2][reg], pv[3][reg]));
      cm = fmaxf(cm, __shfl_xor(cm, 1, 64));
      cm = fmaxf(cm, __shfl_xor(cm, 2, 64));
      cm = fmaxf(cm, __shfl_xor(cm, 4, 64));
      cm = fmaxf(cm, __shfl_xor(cm, 8, 64));
      float nm = fmaxf(m_[reg], cm);
      float alpha = __expf(m_[reg] - nm);
      float rs = 0.f;
#pragma unroll
      for (int j = 0; j < 4; j++) {
        float e = __expf(pv[j][reg] - nm);
        pv[j][reg] = e;
        rs += e;
      }
      rs += __shfl_xor(rs, 1, 64);
      rs += __shfl_xor(rs, 2, 64);
      rs += __shfl_xor(rs, 4, 64);
      rs += __shfl_xor(rs, 8, 64);
      l_[reg] = l_[reg] * alpha + rs;
      m_[reg] = nm;
      if (col == 0) arow[w * 16 + quad * 4 + reg] = alpha;
    }

#pragma unroll
    for (int j = 0; j < 4; j++)
#pragma unroll
      for (int reg = 0; reg < 4; reg++)
        Ps[(w * 16 + quad * 4 + reg) * 72 + j * 16 + col] = f2bf(pv[j][reg]);

    asm volatile("s_waitcnt lgkmcnt(0)" ::: "memory");
    float aval = arow[w * 16 + col];
#pragma unroll
    for (int mt = 0; mt < 4; mt++) oacc[mt] *= aval;

#pragma unroll
    for (int kk = 0; kk < 2; kk++) {
      short8 pb = *(const short8*)&Ps[(w * 16 + col) * 72 + kk * 32 + quad * 8];
#pragma unroll
      for (int mt = 0; mt < 4; mt++) {
        short8 va = *(const short8*)&Vt[(mt * 16 + col) * 72 + kk * 32 + quad * 8];
        oacc[mt] = __builtin_amdgcn_mfma_f32_16x16x32_bf16(va, pb, oacc[mt], 0, 0, 0);
      }
    }
    __syncthreads();
  }

#pragma unroll
  for (int reg = 0; reg < 4; reg++)
    if (col == 0) arow[w * 16 + quad * 4 + reg] = 1.0f / l_[reg];
  asm volatile("s_waitcnt lgkmcnt(0)" ::: "memory");
  float lv = arow[w * 16 + col];
  size_t obase = (size_t)(b * SEQ + qt * 64 + w * 16 + col) * 1024 + h * 64;
#pragma unroll
  for (int mt = 0; mt < 4; mt++) {
    short4v pk;
#pragma unroll
    for (int reg = 0; reg < 4; reg++) pk[reg] = (short)f2bf(oacc[mt][reg] * lv);
    *(short4v*)&o[obase + mt * 16 + quad * 4] = pk;
  }
}

// ---------------- launch ----------------
extern "C" void kernel_launch(void* const* d_in, const int* in_sizes, int n_in,
                              void* d_out, int out_size, void* d_ws, size_t ws_size,
                              hipStream_t stream) {
  const float* x_in    = (const float*)d_in[0];
  const float* rel_emb = (const float*)d_in[1];
  const float* qn_g    = (const float*)d_in[2];
  const float* wq      = (const float*)d_in[3];
  const float* wkv     = (const float*)d_in[4];
  const float* wo      = (const float*)d_in[5];
  const float* ln1_g   = (const float*)d_in[6];
  const float* w1      = (const float*)d_in[7];
  const float* convw   = (const float*)d_in[8];
  const float* ln2_g   = (const float*)d_in[9];
  const float* w2      = (const float*)d_in[10];
  const float* final_g = (const float*)d_in[11];
  float* out = (float*)d_out;

  // ws layout, no aliasing (~70 MB)
  float* xbuf   = (float*)d_ws;                              // TOK*DIM f32
  float* bias_c = xbuf + (size_t)TOK * DIM;                  // 16*16*4096 f32
  ushort* hbuf  = (ushort*)(bias_c + (size_t)16 * 16 * 4096);
  ushort* obuf  = hbuf + (size_t)TOK * DIM;
  ushort* qkvbuf = obuf + (size_t)TOK * DIM;
  ushort* h1buf = qkvbuf + (size_t)TOK * QKVW;
  ushort* gbuf  = h1buf + (size_t)TOK * N1P;
  ushort* wtbuf = gbuf + (size_t)TOK * INNERP;

  copy_kernel<<<(TOK * DIM + 255) / 256, 256, 0, stream>>>(xbuf, x_in, TOK * DIM);
  bias_frag_kernel<<<256, 256, 0, stream>>>(rel_emb, bias_c);

  for (int l = 0; l < DEPTH; l++) {
    ln1024<ushort><<<TOK, 256, 0, stream>>>(xbuf, qn_g + l * DIM, hbuf);
    transpose_qkv<<<dim3(18, 16), 256, 0, stream>>>(
        wq + (size_t)l * DIM * DIM, wkv + (size_t)l * DIM * 128, wtbuf);
    gemm_mfma64<false, ushort><<<dim3(18, 16), 256, 0, stream>>>(
        hbuf, wtbuf, nullptr, qkvbuf, QKVW, DIM, 1.0f);
    attn_mfma<<<dim3(BATCH * HEADS, 16), 256, 0, stream>>>(qkvbuf, bias_c, obuf);
    transpose_vec<<<dim3(16, 16), 256, 0, stream>>>(
        wo + (size_t)l * DIM * DIM, wtbuf, DIM, DIM, DIM, DIM, 1.0f);
    gemm_mfma64<true, float><<<dim3(16, 16), 256, 0, stream>>>(
        obuf, wtbuf, xbuf, xbuf, DIM, DIM, 1.0f);
    ln1024<ushort><<<TOK, 256, 0, stream>>>(xbuf, ln1_g + l * DIM, hbuf);
    transpose_vec<<<dim3(86, 16), 256, 0, stream>>>(
        w1 + (size_t)l * DIM * INNER2, wtbuf, DIM, INNER2, DIM, N1P, 1.0f);
    gemm_mfma128<false, ushort><<<dim3(43, 16), 256, 0, stream>>>(
        hbuf, wtbuf, nullptr, h1buf, N1P, DIM, 1.0f);
    convglu_ln<<<TOK, 256, 0, stream>>>(
        h1buf, convw + (size_t)l * INNER2 * 3, ln2_g + l * INNER, gbuf);
    transpose_vec<<<dim3(16, 43), 256, 0, stream>>>(
        w2 + (size_t)l * INNER * DIM, wtbuf, INNER, DIM, INNERP, DIM, 1.0f);
    gemm_mfma64<true, float><<<dim3(16, 16), 256, 0, stream>>>(
        gbuf, wtbuf, xbuf, xbuf, DIM, INNERP, 1.0f);
  }
  ln1024<float><<<TOK, 256, 0, stream>>>(xbuf, final_g, out);
}